// Round 3
// baseline (15756.239 us; speedup 1.0000x reference)
//
#include <hip/hip_runtime.h>

#define TT 512
#define BB 256
#define HH 512
#define FH 2048   // 4*H

typedef __attribute__((ext_vector_type(8))) short short8;
typedef __attribute__((ext_vector_type(4))) short short4v;
typedef __attribute__((ext_vector_type(4))) float f32x4;

__device__ __forceinline__ short f2bf(float f) {
  union { float f; unsigned u; } v; v.f = f;
  unsigned r = v.u + 0x7fffu + ((v.u >> 16) & 1u);   // RNE
  return (short)(r >> 16);
}

__device__ __forceinline__ float sigm(float x) {
  return 1.f / (1.f + __expf(-x));
}
__device__ __forceinline__ float tanh_fast(float x) {
  float e = __expf(2.f * x);
  return 1.f - 2.f / (e + 1.f);
}

// Build WiT[col][k], WhT[col][k] (bf16, col-major over K=512), init h (bf16), c (fp32),
// zero the done-flag array.
__global__ void prep_kernel(const float* __restrict__ Wi, const float* __restrict__ Wh,
                            const float* __restrict__ h0, const float* __restrict__ c0,
                            short* __restrict__ WiT, short* __restrict__ WhT,
                            short* __restrict__ hb, float* __restrict__ cb,
                            int* __restrict__ done) {
  int idx = blockIdx.x * blockDim.x + threadIdx.x;
  int stride = gridDim.x * blockDim.x;
  for (int i = idx; i < FH * HH; i += stride) {
    int col = i >> 9;
    int k = i & 511;
    WiT[i] = f2bf(Wi[(size_t)k * FH + col]);
    WhT[i] = f2bf(Wh[(size_t)k * FH + col]);
  }
  for (int i = idx; i < BB * HH; i += stride) {
    hb[i] = f2bf(h0[i]);
    cb[i] = c0[i];
  }
  for (int i = idx; i < 8 * 512 * 32; i += stride) done[i] = 0;
}

// Gx[row][col] = X[rowBase+row][:] @ WiT[col][:] + bias[col], for a chunk of rows.
__global__ __launch_bounds__(256) void precomp_kernel(
    const float* __restrict__ X, const short* __restrict__ WiT,
    const float* __restrict__ bias, float* __restrict__ Gx, int rowBase) {
  __shared__ short lx[32 * 520];
  const int tid = threadIdx.x;
  const int rb = blockIdx.x * 32;
  const size_t grow = (size_t)(rowBase + rb);

  for (int e = tid * 4; e < 32 * 512; e += 1024) {
    int row = e >> 9;
    int col = e & 511;
    f32x4 v = *(const f32x4*)(X + (grow + row) * 512 + col);
    short4v s = { f2bf(v[0]), f2bf(v[1]), f2bf(v[2]), f2bf(v[3]) };
    *(short4v*)(&lx[row * 520 + col]) = s;
  }
  __syncthreads();

  const int wid = tid >> 6;
  const int lane = tid & 63;
  const int lc = lane & 15;
  const int kg = lane >> 4;
  const int n0 = blockIdx.y * 256 + wid * 64;

  f32x4 acc[2][4] = {};
#pragma unroll
  for (int kk = 0; kk < 16; ++kk) {
    const int ko = kk * 32 + kg * 8;
    short8 a0 = *(const short8*)(&lx[lc * 520 + ko]);
    short8 a1 = *(const short8*)(&lx[(16 + lc) * 520 + ko]);
#pragma unroll
    for (int nf = 0; nf < 4; ++nf) {
      const short8 b = *(const short8*)(WiT + (size_t)(n0 + nf * 16 + lc) * 512 + ko);
      acc[0][nf] = __builtin_amdgcn_mfma_f32_16x16x32_bf16(a0, b, acc[0][nf], 0, 0, 0);
      acc[1][nf] = __builtin_amdgcn_mfma_f32_16x16x32_bf16(a1, b, acc[1][nf], 0, 0, 0);
    }
  }

  for (int nf = 0; nf < 4; ++nf) {
    int col = n0 + nf * 16 + lc;
    float bv = bias[col];
    for (int m = 0; m < 2; ++m)
      for (int j = 0; j < 4; ++j) {
        int row = rb + m * 16 + kg * 4 + j;
        Gx[(size_t)row * FH + col] = acc[m][nf][j] + bv;
      }
  }
}

// Persistent step kernel: 256 blocks = 8 batch-groups x 32 col-groups.
// Block (i,j): rows [32i,32i+32), h-cols [16j,16j+16) (gate-cols g*512+16j+lc).
// Wh slice persistent in LDS; c tile persistent in registers; per-group flag barrier.
__global__ __launch_bounds__(256) void lstm_persist(
    const int* __restrict__ resets,   // (T,B)
    const short* __restrict__ WhT,    // (2048,512) bf16 bits
    const float* __restrict__ Gx,     // (ct,B,2048) fp32, bias included
    short* __restrict__ hbA,          // h state buffer parity 0
    short* __restrict__ hbB,          // h state buffer parity 1
    float* __restrict__ cb,           // (B,H) c state (chunk carry)
    float* __restrict__ out,          // full output base
    int* __restrict__ done,           // (8,512,32) flags
    int t0, int ct) {
  extern __shared__ short whs[];          // 64 rows x 512 k, XOR-swizzled (64 KB)
  __shared__ short ah[32 * 512];          // 32 rows x 512 k, XOR-swizzled (32 KB)
  __shared__ float gex[4 * 32 * 17];      // gate exchange (8.5 KB)

  const int tid = threadIdx.x;
  const int bid = blockIdx.x;
  const int grp = bid >> 5;          // batch group 0..7
  const int j = bid & 31;            // col group
  const int rb = grp * 32;
  const int hc0 = j * 16;

  const int wid = tid >> 6;
  const int lane = tid & 63;
  const int lc = lane & 15;
  const int kg = lane >> 4;

  // ---- load Wh slice into LDS (once, swizzled) ----
  {
    const int lcol = tid >> 2;            // 0..63
    const int part = tid & 3;             // 0..3
    const int g = lcol >> 4;
    const int gcol = g * 512 + hc0 + (lcol & 15);
    const short* src = WhT + (size_t)gcol * 512 + part * 128;
    const int dbase = lcol * 1024 + part * 256;
    const int sw = (lcol & 7) << 4;
#pragma unroll
    for (int it = 0; it < 16; ++it) {
      short8 v = *(const short8*)(src + it * 8);
      *(short8*)((char*)whs + ((dbase + it * 16) ^ sw)) = v;
    }
  }

  // ---- c tile in registers ----
  const int ecol = tid & 15;
  const int erow = (tid >> 4) * 2;        // rows erow, erow+1
  float creg[2];
  creg[0] = cb[(size_t)(rb + erow) * HH + hc0 + ecol];
  creg[1] = cb[(size_t)(rb + erow + 1) * HH + hc0 + ecol];

  const int srow = tid >> 3;              // staging row 0..31
  const int sc0 = tid & 7;                // staging chunk phase
  const int ssw = (srow & 7) << 4;

  __syncthreads();

  for (int t = t0; t < t0 + ct; ++t) {
    // ---- prefetch (no dependency on barrier): Gx + resets ----
    const float* gxt = Gx + (size_t)(t - t0) * BB * FH;
    float gxv[2][4];
#pragma unroll
    for (int r = 0; r < 2; ++r)
#pragma unroll
      for (int g = 0; g < 4; ++g)
        gxv[r][g] = gxt[(size_t)(rb + erow + r) * FH + g * 512 + hc0 + ecol];
    const int* rstT = resets + (size_t)t * BB;
    const int rste0 = rstT[rb + erow];
    const int rste1 = rstT[rb + erow + 1];
    const int rsts = rstT[rb + srow];

    // ---- group barrier: wait until h-state for step t is complete ----
    if (t > t0) {
      if (wid == 0) {
        const int* dn = done + ((size_t)grp * 512 + (t - 1)) * 32;
        bool ok;
        do {
          int v = (lane < 32)
                      ? __hip_atomic_load(&dn[lane], __ATOMIC_RELAXED,
                                          __HIP_MEMORY_SCOPE_AGENT)
                      : 1;
          ok = __all(v != 0);
          if (!ok) __builtin_amdgcn_s_sleep(1);
        } while (!ok);
        __threadfence();   // acquire: invalidate stale L1/L2
      }
      __syncthreads();
    }

    // ---- stage h (reset-masked) into LDS, swizzled ----
    {
      const short* hsrc = ((t & 1) ? hbB : hbA) + (size_t)(rb + srow) * HH + sc0 * 8;
      const int dbase = srow * 1024 + sc0 * 16;
#pragma unroll
      for (int it = 0; it < 8; ++it) {
        short8 v = *(const short8*)(hsrc + it * 64);
        if (rsts) v = (short8){0, 0, 0, 0, 0, 0, 0, 0};
        *(short8*)((char*)ah + ((dbase + it * 128) ^ ssw)) = v;
      }
    }
    __syncthreads();

    // ---- MFMA: waves 0,1 each compute 2 gates x 2 row-frags ----
    if (wid < 2) {
      const int sw = (lc & 7) << 4;
      f32x4 acc[2][2] = {};
#pragma unroll
      for (int kk = 0; kk < 16; ++kk) {
        const int kb = kk * 64 + kg * 16;
        short8 a0 = *(const short8*)((char*)ah + ((lc * 1024 + kb) ^ sw));
        short8 a1 = *(const short8*)((char*)ah + (((lc + 16) * 1024 + kb) ^ sw));
        short8 b0 = *(const short8*)((char*)whs +
                      ((((wid * 2 + 0) * 16 + lc) * 1024 + kb) ^ sw));
        short8 b1 = *(const short8*)((char*)whs +
                      ((((wid * 2 + 1) * 16 + lc) * 1024 + kb) ^ sw));
        acc[0][0] = __builtin_amdgcn_mfma_f32_16x16x32_bf16(a0, b0, acc[0][0], 0, 0, 0);
        acc[0][1] = __builtin_amdgcn_mfma_f32_16x16x32_bf16(a1, b0, acc[0][1], 0, 0, 0);
        acc[1][0] = __builtin_amdgcn_mfma_f32_16x16x32_bf16(a0, b1, acc[1][0], 0, 0, 0);
        acc[1][1] = __builtin_amdgcn_mfma_f32_16x16x32_bf16(a1, b1, acc[1][1], 0, 0, 0);
      }
#pragma unroll
      for (int gs = 0; gs < 2; ++gs)
#pragma unroll
        for (int m = 0; m < 2; ++m)
#pragma unroll
          for (int jj = 0; jj < 4; ++jj)
            gex[(wid * 2 + gs) * 544 + (m * 16 + kg * 4 + jj) * 17 + lc] =
                acc[gs][m][jj];
    }
    __syncthreads();

    // ---- epilogue: all 256 threads, 2 cells each ----
    short* hdst = (t & 1) ? hbA : hbB;     // buffer for state before step t+1
    float* ysrow = out + (size_t)t * BB * HH;
#pragma unroll
    for (int r = 0; r < 2; ++r) {
      const int row = erow + r;
      float gi = gex[0 * 544 + row * 17 + ecol] + gxv[r][0];
      float gf = gex[1 * 544 + row * 17 + ecol] + gxv[r][1];
      float gg = gex[2 * 544 + row * 17 + ecol] + gxv[r][2];
      float go = gex[3 * 544 + row * 17 + ecol] + gxv[r][3];
      float cold = ((r == 0 ? rste0 : rste1) != 0) ? 0.f : creg[r];
      float cn = sigm(gf) * cold + sigm(gi) * tanh_fast(gg);
      float hn = sigm(go) * tanh_fast(cn);
      creg[r] = cn;
      size_t gidx = (size_t)(rb + row) * HH + hc0 + ecol;
      hdst[gidx] = f2bf(hn);
      ysrow[gidx] = hn;
      if (t == TT - 1) {
        out[(size_t)TT * BB * HH + gidx] = cn;                      // c_f
        out[(size_t)TT * BB * HH + (size_t)BB * HH + gidx] = hn;    // h_f
      }
    }
    __syncthreads();   // all stores issued+waited before flag
    if (tid == 0) {
      __threadfence();  // release: write back L2 so other XCDs see h
      __hip_atomic_store(&done[((size_t)grp * 512 + t) * 32 + j], 1,
                         __ATOMIC_RELEASE, __HIP_MEMORY_SCOPE_AGENT);
    }
  }

  // carry c to next chunk
  cb[(size_t)(rb + erow) * HH + hc0 + ecol] = creg[0];
  cb[(size_t)(rb + erow + 1) * HH + hc0 + ecol] = creg[1];
}

// ---- fallback path (tiny ws): full-K per-step kernel, from R2 ----
__global__ __launch_bounds__(64) void lstm_step_fullk(
    const float* __restrict__ xt, const int* __restrict__ rst,
    const float* __restrict__ bias, const short* __restrict__ WiT,
    const short* __restrict__ WhT, const short* __restrict__ hin,
    short* __restrict__ hout, float* __restrict__ cbuf, float* __restrict__ ys) {
  const int lane = threadIdx.x;
  const int lc = lane & 15;
  const int kg = lane >> 4;
  const int r0 = blockIdx.x * 16;
  const int h0 = blockIdx.y * 16;
  const int hc = h0 + lc;

  float coldv[4];
  int rstj[4];
#pragma unroll
  for (int jj = 0; jj < 4; ++jj) {
    int row = r0 + kg * 4 + jj;
    rstj[jj] = rst[row];
    coldv[jj] = cbuf[(size_t)row * HH + hc];
  }

  const int rowA = r0 + lc;
  const bool rm = rst[rowA] != 0;
  const short8 zero = {};
  f32x4 acc[4] = {};
#pragma unroll
  for (int kk = 0; kk < 16; ++kk) {
    const int ko = kk * 32 + kg * 8;
    f32x4 u0 = *(const f32x4*)(xt + (size_t)rowA * HH + ko);
    f32x4 u1 = *(const f32x4*)(xt + (size_t)rowA * HH + ko + 4);
    short8 a;
#pragma unroll
    for (int e = 0; e < 4; ++e) { a[e] = f2bf(u0[e]); a[e + 4] = f2bf(u1[e]); }
#pragma unroll
    for (int g = 0; g < 4; ++g) {
      const short8 b = *(const short8*)(WiT + (size_t)(g * HH + h0 + lc) * HH + ko);
      acc[g] = __builtin_amdgcn_mfma_f32_16x16x32_bf16(a, b, acc[g], 0, 0, 0);
    }
  }
#pragma unroll
  for (int kk = 0; kk < 16; ++kk) {
    const int ko = kk * 32 + kg * 8;
    short8 a = rm ? zero : *(const short8*)(hin + (size_t)rowA * HH + ko);
#pragma unroll
    for (int g = 0; g < 4; ++g) {
      const short8 b = *(const short8*)(WhT + (size_t)(g * HH + h0 + lc) * HH + ko);
      acc[g] = __builtin_amdgcn_mfma_f32_16x16x32_bf16(a, b, acc[g], 0, 0, 0);
    }
  }

#pragma unroll
  for (int jj = 0; jj < 4; ++jj) {
    int row = r0 + kg * 4 + jj;
    float gi = acc[0][jj] + bias[0 * HH + hc];
    float gf = acc[1][jj] + bias[1 * HH + hc];
    float gg = acc[2][jj] + bias[2 * HH + hc];
    float go = acc[3][jj] + bias[3 * HH + hc];
    float cold = rstj[jj] ? 0.f : coldv[jj];
    float cn = sigm(gf) * cold + sigm(gi) * tanh_fast(gg);
    float hn = sigm(go) * tanh_fast(cn);
    cbuf[(size_t)row * HH + hc] = cn;
    hout[(size_t)row * HH + hc] = f2bf(hn);
    ys[(size_t)row * HH + hc] = hn;
  }
}

__global__ void finalize_kernel(const float* __restrict__ cbuf, float* __restrict__ out) {
  int i = blockIdx.x * blockDim.x + threadIdx.x;
  if (i < BB * HH) {
    size_t base = (size_t)TT * BB * HH;
    out[base + i] = cbuf[i];
    out[base + BB * HH + i] = out[(size_t)(TT - 1) * BB * HH + i];
  }
}

extern "C" void kernel_launch(void* const* d_in, const int* in_sizes, int n_in,
                              void* d_out, int out_size, void* d_ws, size_t ws_size,
                              hipStream_t stream) {
  const float* x      = (const float*)d_in[0];
  const int*   resets = (const int*)d_in[1];
  const float* c0     = (const float*)d_in[2];
  const float* h0     = (const float*)d_in[3];
  const float* Wi     = (const float*)d_in[4];
  const float* Wh     = (const float*)d_in[5];
  const float* bias   = (const float*)d_in[6];
  float* out = (float*)d_out;

  char* ws = (char*)d_ws;
  short* WiT = (short*)ws;                                  // 2 MiB
  short* WhT = (short*)(ws + (2u << 20));                   // 2 MiB
  short* hb0 = (short*)(ws + (4u << 20));                   // 256 KiB
  short* hb1 = hb0 + BB * HH;                               // 256 KiB
  float* cb  = (float*)(ws + (4u << 20) + (512u << 10));    // 512 KiB
  int*   dn  = (int*)(ws + (5u << 20));                     // 512 KiB flags
  const size_t base = (size_t)(5u << 20) + (512u << 10);    // 5.5 MiB

  const size_t perT = (size_t)BB * FH * 4;                  // 2 MiB per step of Gx
  int chunkT = 0;
  if (ws_size > base) chunkT = (int)((ws_size - base) / perT);
  if (chunkT > TT) chunkT = TT;

  prep_kernel<<<1024, 256, 0, stream>>>(Wi, Wh, h0, c0, WiT, WhT, hb0, cb, dn);

  if (chunkT >= 1) {
    float* Gx = (float*)(ws + base);
    for (int t0 = 0; t0 < TT; t0 += chunkT) {
      int ct = (TT - t0 < chunkT) ? (TT - t0) : chunkT;
      precomp_kernel<<<dim3(ct * 8, 8), 256, 0, stream>>>(x, WiT, bias, Gx, t0 * BB);
      lstm_persist<<<256, 256, 65536, stream>>>(resets, WhT, Gx, hb0, hb1, cb,
                                                out, dn, t0, ct);
    }
  } else {
    for (int t = 0; t < TT; ++t) {
      const short* hin = (t & 1) ? hb1 : hb0;
      short* hout      = (t & 1) ? hb0 : hb1;
      lstm_step_fullk<<<dim3(16, 32), 64, 0, stream>>>(
          x + (size_t)t * BB * HH, resets + (size_t)t * BB, bias, WiT, WhT,
          hin, hout, cb, out + (size_t)t * BB * HH);
    }
    finalize_kernel<<<(BB * HH + 255) / 256, 256, 0, stream>>>(cb, out);
  }
}

// Round 4
// 3487.755 us; speedup vs baseline: 4.5176x; 4.5176x over previous
//
#include <hip/hip_runtime.h>

#define TT 512
#define BB 256
#define HH 512
#define FH 2048   // 4*H

typedef __attribute__((ext_vector_type(8))) short short8;
typedef __attribute__((ext_vector_type(4))) short short4v;
typedef __attribute__((ext_vector_type(4))) float f32x4;
typedef __attribute__((ext_vector_type(2))) float f32x2;

__device__ __forceinline__ short f2bf(float f) {
  union { float f; unsigned u; } v; v.f = f;
  unsigned r = v.u + 0x7fffu + ((v.u >> 16) & 1u);   // RNE
  return (short)(r >> 16);
}

__device__ __forceinline__ float sigm(float x) {
  return 1.f / (1.f + __expf(-x));
}
__device__ __forceinline__ float tanh_fast(float x) {
  float e = __expf(2.f * x);
  return 1.f - 2.f / (e + 1.f);
}

// Build WiT[col][k], WhT[col][k] (bf16, col-major over K=512), init h (bf16), c (fp32),
// zero the done-flag array.
__global__ void prep_kernel(const float* __restrict__ Wi, const float* __restrict__ Wh,
                            const float* __restrict__ h0, const float* __restrict__ c0,
                            short* __restrict__ WiT, short* __restrict__ WhT,
                            short* __restrict__ hb, float* __restrict__ cb,
                            int* __restrict__ done) {
  int idx = blockIdx.x * blockDim.x + threadIdx.x;
  int stride = gridDim.x * blockDim.x;
  for (int i = idx; i < FH * HH; i += stride) {
    int col = i >> 9;
    int k = i & 511;
    WiT[i] = f2bf(Wi[(size_t)k * FH + col]);
    WhT[i] = f2bf(Wh[(size_t)k * FH + col]);
  }
  for (int i = idx; i < BB * HH; i += stride) {
    hb[i] = f2bf(h0[i]);
    cb[i] = c0[i];
  }
  for (int i = idx; i < 8 * TT * 32; i += stride) done[i] = 0;
}

// Gx[row][col] = X[rowBase+row][:] @ WiT[col][:] + bias[col], for a chunk of rows.
__global__ __launch_bounds__(256) void precomp_kernel(
    const float* __restrict__ X, const short* __restrict__ WiT,
    const float* __restrict__ bias, float* __restrict__ Gx, int rowBase) {
  __shared__ short lx[32 * 520];
  const int tid = threadIdx.x;
  const int rb = blockIdx.x * 32;
  const size_t grow = (size_t)(rowBase + rb);

  for (int e = tid * 4; e < 32 * 512; e += 1024) {
    int row = e >> 9;
    int col = e & 511;
    f32x4 v = *(const f32x4*)(X + (grow + row) * 512 + col);
    short4v s = { f2bf(v[0]), f2bf(v[1]), f2bf(v[2]), f2bf(v[3]) };
    *(short4v*)(&lx[row * 520 + col]) = s;
  }
  __syncthreads();

  const int wid = tid >> 6;
  const int lane = tid & 63;
  const int lc = lane & 15;
  const int kg = lane >> 4;
  const int n0 = blockIdx.y * 256 + wid * 64;

  f32x4 acc[2][4] = {};
#pragma unroll
  for (int kk = 0; kk < 16; ++kk) {
    const int ko = kk * 32 + kg * 8;
    short8 a0 = *(const short8*)(&lx[lc * 520 + ko]);
    short8 a1 = *(const short8*)(&lx[(16 + lc) * 520 + ko]);
#pragma unroll
    for (int nf = 0; nf < 4; ++nf) {
      const short8 b = *(const short8*)(WiT + (size_t)(n0 + nf * 16 + lc) * 512 + ko);
      acc[0][nf] = __builtin_amdgcn_mfma_f32_16x16x32_bf16(a0, b, acc[0][nf], 0, 0, 0);
      acc[1][nf] = __builtin_amdgcn_mfma_f32_16x16x32_bf16(a1, b, acc[1][nf], 0, 0, 0);
    }
  }

  for (int nf = 0; nf < 4; ++nf) {
    int col = n0 + nf * 16 + lc;
    float bv = bias[col];
    for (int m = 0; m < 2; ++m)
      for (int j = 0; j < 4; ++j) {
        int row = rb + m * 16 + kg * 4 + j;
        Gx[(size_t)row * FH + col] = acc[m][nf][j] + bv;
      }
  }
}

// Persistent step kernel: 256 blocks = 8 batch-groups x 32 col-groups.
// h exchanged through L3 via RELAXED agent-scope atomics (sc0 sc1 — no fences,
// no L2 writebacks). Ordering: data stores -> s_waitcnt vmcnt(0) -> barrier ->
// flag store; consumer: poll flag -> barrier -> data loads (batched).
__global__ __launch_bounds__(256) void lstm_persist(
    const int* __restrict__ resets,   // (T,B)
    const short* __restrict__ WhT,    // (2048,512) bf16 bits
    const float* __restrict__ Gx,     // (ct,B,2048) fp32, bias included
    unsigned* __restrict__ hbA,       // (B,H/2) u32 bf16-pairs, parity 0
    unsigned* __restrict__ hbB,       // parity 1
    float* __restrict__ cb,           // (B,H) c state (chunk carry)
    float* __restrict__ out,          // full output base
    int* __restrict__ done,           // (8,T,32) flags
    int t0, int ct) {
  extern __shared__ short whs[];          // 64 rows x 512 k, XOR-swizzled (64 KB)
  __shared__ short ah[32 * 512];          // 32 rows x 512 k, XOR-swizzled (32 KB)
  __shared__ float gex[4 * 32 * 17];      // gate exchange (8.5 KB)

  const int tid = threadIdx.x;
  const int bid = blockIdx.x;
  const int grp = bid >> 5;          // batch group 0..7
  const int j = bid & 31;            // col group
  const int rb = grp * 32;
  const int hc0 = j * 16;

  const int wid = tid >> 6;
  const int lane = tid & 63;
  const int lc = lane & 15;
  const int kg = lane >> 4;

  // ---- load Wh slice into LDS (once, swizzled) ----
  {
    const int lcol = tid >> 2;            // 0..63
    const int part = tid & 3;             // 0..3
    const int g = lcol >> 4;
    const int gcol = g * 512 + hc0 + (lcol & 15);
    const short* src = WhT + (size_t)gcol * 512 + part * 128;
    const int dbase = lcol * 1024 + part * 256;
    const int sw = (lcol & 7) << 4;
#pragma unroll
    for (int it = 0; it < 16; ++it) {
      short8 v = *(const short8*)(src + it * 8);
      *(short8*)((char*)whs + ((dbase + it * 16) ^ sw)) = v;
    }
  }

  // ---- epilogue ownership: row = tid>>3 (0..31), col pair cp = (tid&7)*2 ----
  const int erow = tid >> 3;
  const int cp = (tid & 7) * 2;
  float creg[2];
  {
    const float* cs = cb + (size_t)(rb + erow) * HH + hc0 + cp;
    creg[0] = cs[0];
    creg[1] = cs[1];
  }

  __syncthreads();

  for (int t = t0; t < t0 + ct; ++t) {
    // ---- prefetch Gx + resets (plain cached loads, no dependency on barrier) ----
    const float* gxt =
        Gx + (size_t)(t - t0) * BB * FH + (size_t)(rb + erow) * FH + hc0 + cp;
    float gxv[4][2];
#pragma unroll
    for (int g = 0; g < 4; ++g) {
      gxv[g][0] = gxt[g * 512 + 0];
      gxv[g][1] = gxt[g * 512 + 1];
    }
    const int* rstT = resets + (size_t)t * BB;
    const int rstE = rstT[rb + erow];

    // ---- group barrier: wait until h-state for step t is complete ----
    if (t > t0) {
      if (wid == 0) {
        int* dn = done + ((size_t)grp * TT + (t - 1)) * 32;
        bool ok;
        do {
          int v = (lane < 32)
                      ? __hip_atomic_load(&dn[lane], __ATOMIC_RELAXED,
                                          __HIP_MEMORY_SCOPE_AGENT)
                      : 1;
          ok = __all(v != 0);
          if (!ok) __builtin_amdgcn_s_sleep(2);
        } while (!ok);
      }
      __syncthreads();
    }

    // ---- stage h via relaxed agent loads (L3), batched; coalesced; LDS swizzled ----
    {
      unsigned* hsrc = ((t & 1) ? hbB : hbA) + (size_t)rb * 256;
      unsigned hv[32];
#pragma unroll
      for (int it = 0; it < 32; ++it)
        hv[it] = __hip_atomic_load(&hsrc[it * 256 + tid], __ATOMIC_RELAXED,
                                   __HIP_MEMORY_SCOPE_AGENT);
#pragma unroll
      for (int it = 0; it < 32; ++it) {
        unsigned v = (rstT[rb + it] != 0) ? 0u : hv[it];
        *(unsigned*)((char*)ah + ((it * 1024 + tid * 4) ^ ((it & 7) << 4))) = v;
      }
    }
    __syncthreads();

    // ---- MFMA: waves 0,1 each compute 2 gates x 2 row-frags ----
    if (wid < 2) {
      const int sw = (lc & 7) << 4;
      f32x4 acc[2][2] = {};
#pragma unroll
      for (int kk = 0; kk < 16; ++kk) {
        const int kb = kk * 64 + kg * 16;
        short8 a0 = *(const short8*)((char*)ah + ((lc * 1024 + kb) ^ sw));
        short8 a1 = *(const short8*)((char*)ah + (((lc + 16) * 1024 + kb) ^ sw));
        short8 b0 = *(const short8*)((char*)whs +
                      ((((wid * 2 + 0) * 16 + lc) * 1024 + kb) ^ sw));
        short8 b1 = *(const short8*)((char*)whs +
                      ((((wid * 2 + 1) * 16 + lc) * 1024 + kb) ^ sw));
        acc[0][0] = __builtin_amdgcn_mfma_f32_16x16x32_bf16(a0, b0, acc[0][0], 0, 0, 0);
        acc[0][1] = __builtin_amdgcn_mfma_f32_16x16x32_bf16(a1, b0, acc[0][1], 0, 0, 0);
        acc[1][0] = __builtin_amdgcn_mfma_f32_16x16x32_bf16(a0, b1, acc[1][0], 0, 0, 0);
        acc[1][1] = __builtin_amdgcn_mfma_f32_16x16x32_bf16(a1, b1, acc[1][1], 0, 0, 0);
      }
#pragma unroll
      for (int gs = 0; gs < 2; ++gs)
#pragma unroll
        for (int m = 0; m < 2; ++m)
#pragma unroll
          for (int jj = 0; jj < 4; ++jj)
            gex[(wid * 2 + gs) * 544 + (m * 16 + kg * 4 + jj) * 17 + lc] =
                acc[gs][m][jj];
    }
    __syncthreads();

    // ---- epilogue: thread owns (erow, cols cp, cp+1) ----
    {
      unsigned* hdst = (t & 1) ? hbA : hbB;
      float* ysrow = out + (size_t)t * BB * HH;
      const int gb = erow * 17 + cp;
      float gi0 = gex[0 * 544 + gb] + gxv[0][0], gi1 = gex[0 * 544 + gb + 1] + gxv[0][1];
      float gf0 = gex[1 * 544 + gb] + gxv[1][0], gf1 = gex[1 * 544 + gb + 1] + gxv[1][1];
      float gg0 = gex[2 * 544 + gb] + gxv[2][0], gg1 = gex[2 * 544 + gb + 1] + gxv[2][1];
      float go0 = gex[3 * 544 + gb] + gxv[3][0], go1 = gex[3 * 544 + gb + 1] + gxv[3][1];
      float cold0 = rstE ? 0.f : creg[0];
      float cold1 = rstE ? 0.f : creg[1];
      float cn0 = sigm(gf0) * cold0 + sigm(gi0) * tanh_fast(gg0);
      float cn1 = sigm(gf1) * cold1 + sigm(gi1) * tanh_fast(gg1);
      float hn0 = sigm(go0) * tanh_fast(cn0);
      float hn1 = sigm(go1) * tanh_fast(cn1);
      creg[0] = cn0;
      creg[1] = cn1;
      size_t gidx = (size_t)(rb + erow) * HH + hc0 + cp;
      *(f32x2*)(ysrow + gidx) = (f32x2){hn0, hn1};
      unsigned pack = (unsigned)(unsigned short)f2bf(hn0) |
                      ((unsigned)(unsigned short)f2bf(hn1) << 16);
      __hip_atomic_store(&hdst[(size_t)(rb + erow) * 256 + (hc0 >> 1) + (tid & 7)],
                         pack, __ATOMIC_RELAXED, __HIP_MEMORY_SCOPE_AGENT);
      if (t == TT - 1) {
        out[(size_t)TT * BB * HH + gidx] = cn0;
        out[(size_t)TT * BB * HH + gidx + 1] = cn1;
        out[(size_t)TT * BB * HH + (size_t)BB * HH + gidx] = hn0;
        out[(size_t)TT * BB * HH + (size_t)BB * HH + gidx + 1] = hn1;
      }
    }
    asm volatile("s_waitcnt vmcnt(0)" ::: "memory");  // h stores done (this thread)
    __syncthreads();                                  // all threads' stores done
    if (tid == 0)
      __hip_atomic_store(&done[((size_t)grp * TT + t) * 32 + j], 1,
                         __ATOMIC_RELAXED, __HIP_MEMORY_SCOPE_AGENT);
  }

  // carry c to next chunk
  {
    float* cs = cb + (size_t)(rb + erow) * HH + hc0 + cp;
    cs[0] = creg[0];
    cs[1] = creg[1];
  }
}

// ---- fallback path (tiny ws): full-K per-step kernel ----
__global__ __launch_bounds__(64) void lstm_step_fullk(
    const float* __restrict__ xt, const int* __restrict__ rst,
    const float* __restrict__ bias, const short* __restrict__ WiT,
    const short* __restrict__ WhT, const short* __restrict__ hin,
    short* __restrict__ hout, float* __restrict__ cbuf, float* __restrict__ ys) {
  const int lane = threadIdx.x;
  const int lc = lane & 15;
  const int kg = lane >> 4;
  const int r0 = blockIdx.x * 16;
  const int h0 = blockIdx.y * 16;
  const int hc = h0 + lc;

  float coldv[4];
  int rstj[4];
#pragma unroll
  for (int jj = 0; jj < 4; ++jj) {
    int row = r0 + kg * 4 + jj;
    rstj[jj] = rst[row];
    coldv[jj] = cbuf[(size_t)row * HH + hc];
  }

  const int rowA = r0 + lc;
  const bool rm = rst[rowA] != 0;
  const short8 zero = {};
  f32x4 acc[4] = {};
#pragma unroll
  for (int kk = 0; kk < 16; ++kk) {
    const int ko = kk * 32 + kg * 8;
    f32x4 u0 = *(const f32x4*)(xt + (size_t)rowA * HH + ko);
    f32x4 u1 = *(const f32x4*)(xt + (size_t)rowA * HH + ko + 4);
    short8 a;
#pragma unroll
    for (int e = 0; e < 4; ++e) { a[e] = f2bf(u0[e]); a[e + 4] = f2bf(u1[e]); }
#pragma unroll
    for (int g = 0; g < 4; ++g) {
      const short8 b = *(const short8*)(WiT + (size_t)(g * HH + h0 + lc) * HH + ko);
      acc[g] = __builtin_amdgcn_mfma_f32_16x16x32_bf16(a, b, acc[g], 0, 0, 0);
    }
  }
#pragma unroll
  for (int kk = 0; kk < 16; ++kk) {
    const int ko = kk * 32 + kg * 8;
    short8 a = rm ? zero : *(const short8*)(hin + (size_t)rowA * HH + ko);
#pragma unroll
    for (int g = 0; g < 4; ++g) {
      const short8 b = *(const short8*)(WhT + (size_t)(g * HH + h0 + lc) * HH + ko);
      acc[g] = __builtin_amdgcn_mfma_f32_16x16x32_bf16(a, b, acc[g], 0, 0, 0);
    }
  }

#pragma unroll
  for (int jj = 0; jj < 4; ++jj) {
    int row = r0 + kg * 4 + jj;
    float gi = acc[0][jj] + bias[0 * HH + hc];
    float gf = acc[1][jj] + bias[1 * HH + hc];
    float gg = acc[2][jj] + bias[2 * HH + hc];
    float go = acc[3][jj] + bias[3 * HH + hc];
    float cold = rstj[jj] ? 0.f : coldv[jj];
    float cn = sigm(gf) * cold + sigm(gi) * tanh_fast(gg);
    float hn = sigm(go) * tanh_fast(cn);
    cbuf[(size_t)row * HH + hc] = cn;
    hout[(size_t)row * HH + hc] = f2bf(hn);
    ys[(size_t)row * HH + hc] = hn;
  }
}

__global__ void finalize_kernel(const float* __restrict__ cbuf, float* __restrict__ out) {
  int i = blockIdx.x * blockDim.x + threadIdx.x;
  if (i < BB * HH) {
    size_t base = (size_t)TT * BB * HH;
    out[base + i] = cbuf[i];
    out[base + BB * HH + i] = out[(size_t)(TT - 1) * BB * HH + i];
  }
}

extern "C" void kernel_launch(void* const* d_in, const int* in_sizes, int n_in,
                              void* d_out, int out_size, void* d_ws, size_t ws_size,
                              hipStream_t stream) {
  const float* x      = (const float*)d_in[0];
  const int*   resets = (const int*)d_in[1];
  const float* c0     = (const float*)d_in[2];
  const float* h0     = (const float*)d_in[3];
  const float* Wi     = (const float*)d_in[4];
  const float* Wh     = (const float*)d_in[5];
  const float* bias   = (const float*)d_in[6];
  float* out = (float*)d_out;

  char* ws = (char*)d_ws;
  short* WiT = (short*)ws;                                  // 2 MiB
  short* WhT = (short*)(ws + (2u << 20));                   // 2 MiB
  short* hb0 = (short*)(ws + (4u << 20));                   // 256 KiB
  short* hb1 = hb0 + BB * HH;                               // 256 KiB
  float* cb  = (float*)(ws + (4u << 20) + (512u << 10));    // 512 KiB
  int*   dn  = (int*)(ws + (5u << 20));                     // 512 KiB flags
  const size_t base = (size_t)(5u << 20) + (512u << 10);    // 5.5 MiB

  const size_t perT = (size_t)BB * FH * 4;                  // 2 MiB per step of Gx
  int chunkT = 0;
  if (ws_size > base) chunkT = (int)((ws_size - base) / perT);
  if (chunkT > TT) chunkT = TT;

  prep_kernel<<<1024, 256, 0, stream>>>(Wi, Wh, h0, c0, WiT, WhT, hb0, cb, dn);

  if (chunkT >= 1) {
    float* Gx = (float*)(ws + base);
    for (int t0 = 0; t0 < TT; t0 += chunkT) {
      int ct = (TT - t0 < chunkT) ? (TT - t0) : chunkT;
      precomp_kernel<<<dim3(ct * 8, 8), 256, 0, stream>>>(x, WiT, bias, Gx, t0 * BB);
      lstm_persist<<<256, 256, 65536, stream>>>(resets, WhT, Gx,
                                                (unsigned*)hb0, (unsigned*)hb1,
                                                cb, out, dn, t0, ct);
    }
  } else {
    for (int t = 0; t < TT; ++t) {
      const short* hin = (t & 1) ? hb1 : hb0;
      short* hout      = (t & 1) ? hb0 : hb1;
      lstm_step_fullk<<<dim3(16, 32), 64, 0, stream>>>(
          x + (size_t)t * BB * HH, resets + (size_t)t * BB, bias, WiT, WhT,
          hin, hout, cb, out + (size_t)t * BB * HH);
    }
    finalize_kernel<<<(BB * HH + 255) / 256, 256, 0, stream>>>(cb, out);
  }
}